// Round 1
// baseline (107.931 us; speedup 1.0000x reference)
//
#include <hip/hip_runtime.h>
#include <stdint.h>
#include <stddef.h>

#define BB 16384
#define CC 500
#define DD 512
#define PADC 512
#define LMARGIN 1.0f
#define EPSQ 1e-12f

#define GROUP_P 32                 // prototypes per LDS group
#define N_GROUPS (PADC / GROUP_P)  // 16
#define ROWB 1040                  // LDS bytes per proto row: 1024 data + 16 pad

typedef __attribute__((ext_vector_type(8))) _Float16 f16x8;
typedef __attribute__((ext_vector_type(4))) float f32x4;

#define GLOBAL_AS __attribute__((address_space(1)))
#define LDS_AS __attribute__((address_space(3)))

__device__ __forceinline__ void ld_lds16(const void* g, void* l) {
  __builtin_amdgcn_global_load_lds((const GLOBAL_AS void*)g, (LDS_AS void*)l, 16, 0, 0);
}

__device__ __forceinline__ unsigned short f2h_bits(float f) {
  union { _Float16 h; unsigned short u; } v;
  v.h = (_Float16)f;
  return v.u;
}

// ---- pre-kernel: prototypes fp32 -> f16 (padded to 512 rows), p2[] in fp32 ----
__global__ void prep_kernel(const float* __restrict__ protos,
                            unsigned short* __restrict__ protoH,
                            float* __restrict__ p2) {
  int c = blockIdx.x;    // 0..511
  int t = threadIdx.x;   // 0..255, each handles 2 dims
  float v0 = 0.f, v1 = 0.f;
  if (c < CC) {
    v0 = protos[c * DD + 2 * t];
    v1 = protos[c * DD + 2 * t + 1];
  }
  unsigned pk = (unsigned)f2h_bits(v0) | ((unsigned)f2h_bits(v1) << 16);
  ((unsigned*)protoH)[c * (DD / 2) + t] = pk;
  float s = v0 * v0 + v1 * v1;
#pragma unroll
  for (int d = 1; d < 64; d <<= 1) s += __shfl_xor(s, d, 64);
  __shared__ float ws4[4];
  if ((t & 63) == 0) ws4[t >> 6] = s;
  __syncthreads();
  if (t == 0) p2[c] = ws4[0] + ws4[1] + ws4[2] + ws4[3];
}

// ---- main kernel: each block = 64 rows (4 waves x 16), all 512 (padded) cols ----
__launch_bounds__(256, 1)
__global__ void loss_kernel(const float* __restrict__ feat,
                            const int* __restrict__ labels,
                            const unsigned short* __restrict__ protoH,
                            const float* __restrict__ p2,
                            float* __restrict__ out) {
  __shared__ __align__(16) unsigned char ldsB[GROUP_P * ROWB];  // 33280 B
  __shared__ float f2s[4][16];
  __shared__ float wsum[4];

  const int tid = threadIdx.x;
  const int wave = tid >> 6;
  const int lane = tid & 63;
  const int lane16 = lane & 15;
  const int quad = lane >> 4;
  const int rowBase = blockIdx.x * 64 + wave * 16;

  // stage group 0 (async, direct global->LDS); each wave stages 8 proto rows
#pragma unroll
  for (int r = 0; r < 8; ++r) {
    int p = wave * 8 + r;
    ld_lds16(protoH + (size_t)p * DD + lane * 8, ldsB + p * ROWB);
  }

  // A fragments in registers (16 k-steps x 8 f16) + f2 in fp32
  // A layout: lane holds A[m = lane&15][k = s*32 + quad*8 + j]
  f16x8 afrag[16];
  float f2part = 0.f;
  const float* frow = feat + (size_t)(rowBase + lane16) * DD;
#pragma unroll
  for (int s = 0; s < 16; ++s) {
    const int k0 = s * 32 + quad * 8;
    f32x4 a0 = *(const f32x4*)(frow + k0);
    f32x4 a1 = *(const f32x4*)(frow + k0 + 4);
    f16x8 af;
#pragma unroll
    for (int j = 0; j < 4; ++j) {
      af[j] = (_Float16)a0[j];
      af[j + 4] = (_Float16)a1[j];
      f2part = fmaf(a0[j], a0[j], f2part);
      f2part = fmaf(a1[j], a1[j], f2part);
    }
    afrag[s] = af;
  }
  // combine the 4 quads (each covered a quarter of k) for row lane16
  f2part += __shfl_xor(f2part, 16, 64);
  f2part += __shfl_xor(f2part, 32, 64);
  if (quad == 0) f2s[wave][lane16] = f2part;

  // labels for my 4 output rows (C/D layout: row = quad*4 + i)
  int lab[4];
#pragma unroll
  for (int i = 0; i < 4; ++i) lab[i] = labels[rowBase + quad * 4 + i];

  __syncthreads();  // staging g0 landed (vmcnt drain) + f2s visible

  float f2r[4];
#pragma unroll
  for (int i = 0; i < 4; ++i) f2r[i] = f2s[wave][quad * 4 + i];

  float runMin[4], posD[4];
#pragma unroll
  for (int i = 0; i < 4; ++i) { runMin[i] = 1e30f; posD[i] = -1e30f; }

  for (int g = 0; g < N_GROUPS; ++g) {
    f32x4 acc0 = {0.f, 0.f, 0.f, 0.f};
    f32x4 acc1 = {0.f, 0.f, 0.f, 0.f};
    // B layout: lane holds B[k = s*32 + quad*8 + j][n = lane16]
    const unsigned char* bbase = ldsB + lane16 * ROWB + quad * 16;
#pragma unroll
    for (int s = 0; s < 16; ++s) {
      f16x8 b0 = *(const f16x8*)(bbase + s * 64);
      f16x8 b1 = *(const f16x8*)(bbase + 16 * ROWB + s * 64);
      acc0 = __builtin_amdgcn_mfma_f32_16x16x32_f16(afrag[s], b0, acc0, 0, 0, 0);
      acc1 = __builtin_amdgcn_mfma_f32_16x16x32_f16(afrag[s], b1, acc1, 0, 0, 0);
    }
    __syncthreads();  // all waves done reading this group's LDS
    if (g + 1 < N_GROUPS) {
#pragma unroll
      for (int r = 0; r < 8; ++r) {
        int p = wave * 8 + r;
        ld_lds16(protoH + (size_t)((g + 1) * GROUP_P + p) * DD + lane * 8,
                 ldsB + p * ROWB);
      }
    }
    // register-only epilogue for this group (overlaps async staging)
    const int col0 = g * GROUP_P + lane16;
    const int col1 = col0 + 16;
    const float p20 = p2[col0];
    const float p21 = p2[col1];
#pragma unroll
    for (int i = 0; i < 4; ++i) {
      float d0 = sqrtf(fmaxf(f2r[i] + p20 - 2.f * acc0[i], EPSQ));
      float d1 = sqrtf(fmaxf(f2r[i] + p21 - 2.f * acc1[i], EPSQ));
      bool isPos0 = (col0 == lab[i]);
      bool isPos1 = (col1 == lab[i]);
      posD[i] = fmaxf(posD[i], isPos0 ? d0 : -1e30f);
      posD[i] = fmaxf(posD[i], isPos1 ? d1 : -1e30f);
      runMin[i] = fminf(runMin[i], (!isPos0 && col0 < CC) ? d0 : 1e30f);
      runMin[i] = fminf(runMin[i], (!isPos1 && col1 < CC) ? d1 : 1e30f);
    }
    __syncthreads();  // staging complete before next compute
  }

  // cross-lane reduce: row r lives on the 16 lanes of quad r>>2
  float termSum = 0.f;
#pragma unroll
  for (int i = 0; i < 4; ++i) {
    float m = runMin[i], p = posD[i];
#pragma unroll
    for (int d = 1; d < 16; d <<= 1) {
      m = fminf(m, __shfl_xor(m, d, 64));
      p = fmaxf(p, __shfl_xor(p, d, 64));
    }
    termSum += fmaxf(p - m + LMARGIN, 0.f);
  }
  float contrib = (lane16 == 0) ? termSum : 0.f;
#pragma unroll
  for (int d = 1; d < 64; d <<= 1) contrib += __shfl_xor(contrib, d, 64);
  if (lane == 0) wsum[wave] = contrib;
  __syncthreads();
  if (tid == 0)
    atomicAdd(out, (wsum[0] + wsum[1] + wsum[2] + wsum[3]) * (1.0f / BB));
}

extern "C" void kernel_launch(void* const* d_in, const int* in_sizes, int n_in,
                              void* d_out, int out_size, void* d_ws, size_t ws_size,
                              hipStream_t stream) {
  const float* feat = (const float*)d_in[0];
  const float* protos = (const float*)d_in[1];
  const int* labels = (const int*)d_in[2];
  float* out = (float*)d_out;

  unsigned short* protoH = (unsigned short*)d_ws;                       // 512*512*2 B
  float* p2 = (float*)((char*)d_ws + (size_t)PADC * DD * sizeof(unsigned short));  // +2 KB

  hipMemsetAsync(d_out, 0, sizeof(float) * (out_size > 0 ? out_size : 1), stream);
  prep_kernel<<<PADC, 256, 0, stream>>>(protos, protoH, p2);
  loss_kernel<<<BB / 64, 256, 0, stream>>>(feat, labels, protoH, p2, out);
}